// Round 5
// baseline (238.560 us; speedup 1.0000x reference)
//
#include <hip/hip_runtime.h>
#include <math.h>

#define D_PROJ 8192
#define C_IN   512
#define P_SP   196   // 14*14
#define NBATCH 32
#define KH     98    // K half

#define TR_BLOCKS (7 * 16 * NBATCH)   // 3584 transpose blocks
#define EX_BLOCKS 1024                // extract blocks

// ---------------------------------------------------------------------------
// Fused prep: (a) transpose x[b][c][p] -> xT[b][p][c]; (b) recover both
// count-sketches from dense S1/S2 into packed h | (s<0 ? 0x8000 : 0).
// ---------------------------------------------------------------------------
__global__ __launch_bounds__(256) void prep(
    const float* __restrict__ x,
    const float* __restrict__ S1, const float* __restrict__ S2,
    float* __restrict__ xT, int* __restrict__ p1, int* __restrict__ p2)
{
    __shared__ float tile[32][33];
    const int bid = blockIdx.x;

    if (bid < TR_BLOCKS) {
        const int b  = bid / 112;
        const int r  = bid - b * 112;
        const int cb = r / 7;
        const int c0 = cb * 32;
        const int p0 = (r - cb * 7) * 32;
        const int tx = threadIdx.x & 31;
        const int ty = threadIdx.x >> 5;
        #pragma unroll
        for (int k = 0; k < 4; ++k) {
            const int p = p0 + tx, c = c0 + ty + k * 8;
            if (p < P_SP)
                tile[ty + k * 8][tx] = x[((size_t)b * C_IN + c) * P_SP + p];
        }
        __syncthreads();
        #pragma unroll
        for (int k = 0; k < 4; ++k) {
            const int p = p0 + ty + k * 8, c = c0 + tx;
            if (p < P_SP)
                xT[((size_t)b * P_SP + p) * C_IN + c] = tile[tx][ty + k * 8];
        }
    } else {
        const int total4 = 2 * C_IN * (D_PROJ / 4);      // 2,097,152 float4
        for (int idx = (bid - TR_BLOCKS) * 256 + threadIdx.x; idx < total4;
             idx += EX_BLOCKS * 256) {
            const int m   = idx >> 20;                   // 0: S1, 1: S2
            const int rem = idx & 1048575;
            const float4 v = ((const float4*)(m ? S2 : S1))[rem];
            if (v.x != 0.f || v.y != 0.f || v.z != 0.f || v.w != 0.f) {
                const int row = rem >> 11;               // 2048 float4 / row
                const int c4  = (rem & 2047) << 2;
                float val; int c;
                if      (v.x != 0.f) { val = v.x; c = c4;     }
                else if (v.y != 0.f) { val = v.y; c = c4 + 1; }
                else if (v.z != 0.f) { val = v.z; c = c4 + 2; }
                else                 { val = v.w; c = c4 + 3; }
                (m ? p2 : p1)[row] = c | (val < 0.f ? 0x8000 : 0);
            }
        }
    }
}

// ---------------------------------------------------------------------------
// Fused Gram + count-sketch scatter, barrier-free K-loop version.
// Block = (jt, it, b*2+kh). The ENTIRE 98-deep A and B tiles are staged into
// LDS once (one barrier), then all 98 K-steps run from LDS with no further
// synchronization. LDS: hist 32768 + 2*50176 + 512 = 133632 B -> 1 block/CU
// (intentional: 64 independent FMA chains/thread give a single wave enough
// ILP to keep its SIMD busy; barriers were the R1-R4 bottleneck).
// ---------------------------------------------------------------------------
__global__ __launch_bounds__(256) void gram_scatter(
    const float* __restrict__ xT,
    const int* __restrict__ P1, const int* __restrict__ P2,
    float* __restrict__ partials)
{
    __shared__ float hist[D_PROJ];                       // 32 KB
    __shared__ __align__(16) float As[KH * 128];         // 49 KB, p-major
    __shared__ __align__(16) float Bs[KH * 128];         // 49 KB
    __shared__ unsigned short p1L[128], p2L[128];        // packed h|sign<<15

    const int tid = threadIdx.x;
    const int tx  = tid & 15;           // j quad
    const int ty  = tid >> 4;           // i quad
    const int jt  = blockIdx.x;         // j tile (0..3)
    const int it  = blockIdx.y;         // i tile (0..3)
    const int b   = blockIdx.z >> 1;
    const int kh  = blockIdx.z & 1;     // K half (p in [kh*98, kh*98+98))

    if (tid < 128) {
        p1L[tid] = (unsigned short)P1[it * 128 + tid];
        p2L[tid] = (unsigned short)P2[jt * 128 + tid];
    }
    {   // zero histogram (float4)
        float4* h4 = (float4*)hist;
        const float4 z = make_float4(0.f, 0.f, 0.f, 0.f);
        #pragma unroll
        for (int k = 0; k < 8; ++k) h4[tid + k * 256] = z;
    }

    // ---- stage the full A and B tiles (98 x 128 each) ----
    // float4 index f4: p = f4>>5, c = (f4&31)*4 ; 3136 float4 per tile.
    const float* xb = xT + ((size_t)b * P_SP + kh * KH) * C_IN;
    const int iofs = it * 128, jofs = jt * 128;
    #pragma unroll
    for (int k = 0; k < 13; ++k) {
        const int f4 = k * 256 + tid;
        if (f4 < 3136) {
            const int p = f4 >> 5, c = (f4 & 31) * 4;
            *(float4*)(As + p * 128 + c) =
                *(const float4*)(xb + (size_t)p * C_IN + iofs + c);
        }
    }
    #pragma unroll
    for (int k = 0; k < 13; ++k) {
        const int f4 = k * 256 + tid;
        if (f4 < 3136) {
            const int p = f4 >> 5, c = (f4 & 31) * 4;
            *(float4*)(Bs + p * 128 + c) =
                *(const float4*)(xb + (size_t)p * C_IN + jofs + c);
        }
    }
    __syncthreads();                    // barrier #1 (only sync before scatter)

    // ---- barrier-free K loop: 98 steps straight from LDS ----
    float acc[8][8];
    #pragma unroll
    for (int r = 0; r < 8; ++r)
        #pragma unroll
        for (int c = 0; c < 8; ++c) acc[r][c] = 0.0f;

    #pragma unroll 7
    for (int p = 0; p < KH; ++p) {
        const float* ap = As + p * 128;
        const float* bp = Bs + p * 128;
        const float4 a0 = *(const float4*)(ap + ty * 4);
        const float4 a1 = *(const float4*)(ap + 64 + ty * 4);
        const float4 b0 = *(const float4*)(bp + tx * 4);
        const float4 b1 = *(const float4*)(bp + 64 + tx * 4);
        const float av[8] = {a0.x, a0.y, a0.z, a0.w, a1.x, a1.y, a1.z, a1.w};
        const float bv[8] = {b0.x, b0.y, b0.z, b0.w, b1.x, b1.y, b1.z, b1.w};
        #pragma unroll
        for (int r = 0; r < 8; ++r)
            #pragma unroll
            for (int c = 0; c < 8; ++c)
                acc[r][c] = fmaf(av[r], bv[c], acc[r][c]);
    }

    // ---- scatter: bin = (h1+h2)&8191; sign parity at bit 15 of the sum ----
    int pa[8], pb[8];
    #pragma unroll
    for (int r = 0; r < 8; ++r) {
        const int il = (r < 4) ? (ty * 4 + r) : (64 + ty * 4 + r - 4);
        pa[r] = p1L[il];
    }
    #pragma unroll
    for (int c = 0; c < 8; ++c) {
        const int jl = (c < 4) ? (tx * 4 + c) : (64 + tx * 4 + c - 4);
        pb[c] = p2L[jl];
    }
    #pragma unroll
    for (int r = 0; r < 8; ++r)
        #pragma unroll
        for (int c = 0; c < 8; ++c) {
            const int sum = pa[r] + pb[c];
            const int d   = sum & (D_PROJ - 1);
            const float v = __int_as_float(
                __float_as_int(acc[r][c]) ^ ((sum << 16) & 0x80000000));
            atomicAdd(&hist[d], v);
        }
    __syncthreads();                    // barrier #2

    // ---- plain streaming store of the private histogram ----
    const int part = (b * 32) + (kh * 16) + (it * 4) + jt;
    float4* pm = (float4*)(partials + (size_t)part * D_PROJ);
    const float4* h4 = (const float4*)hist;
    #pragma unroll
    for (int k = 0; k < 8; ++k) pm[tid + k * 256] = h4[tid + k * 256];
}

// ---------------------------------------------------------------------------
// Fused reduce + finalize: one block per batch (1024 threads). Sums the 32
// partial histograms, computes sum(|.|), writes the normalized signed-sqrt
// output directly to d_out. Thread t owns float4 bins {t, 1024+t}.
// ---------------------------------------------------------------------------
__global__ __launch_bounds__(1024) void reduce_finalize(
    const float* __restrict__ partials, float* __restrict__ out)
{
    const int b   = blockIdx.x;
    const int tid = threadIdx.x;
    const float4* base = (const float4*)(partials + ((size_t)b * 32) * D_PROJ);

    float4 s0 = make_float4(0.f, 0.f, 0.f, 0.f);
    float4 s1 = make_float4(0.f, 0.f, 0.f, 0.f);
    #pragma unroll 4
    for (int p = 0; p < 32; ++p) {
        const float4* r = base + (size_t)p * (D_PROJ / 4);
        const float4 u = r[tid];
        const float4 v = r[1024 + tid];
        s0.x += u.x; s0.y += u.y; s0.z += u.z; s0.w += u.w;
        s1.x += v.x; s1.y += v.y; s1.z += v.z; s1.w += v.w;
    }

    float a = fabsf(s0.x) + fabsf(s0.y) + fabsf(s0.z) + fabsf(s0.w)
            + fabsf(s1.x) + fabsf(s1.y) + fabsf(s1.z) + fabsf(s1.w);
    #pragma unroll
    for (int off = 32; off > 0; off >>= 1) a += __shfl_down(a, off, 64);

    __shared__ float red[16];
    if ((tid & 63) == 0) red[tid >> 6] = a;
    __syncthreads();
    float total = 0.f;
    #pragma unroll
    for (int w = 0; w < 16; ++w) total += red[w];
    const float inv =
        1.0f / fmaxf(sqrtf(total + (float)D_PROJ * 1e-8f), 1e-12f);

    float4* o = (float4*)(out + (size_t)b * D_PROJ);
    float4 w0 = s0, w1 = s1;
    {
        float* e = (float*)&w0;
        #pragma unroll
        for (int q = 0; q < 4; ++q) {
            const float x = e[q];
            const float r = sqrtf(fabsf(x) + 1e-8f) * inv;
            e[q] = (x > 0.f) ? r : ((x < 0.f) ? -r : 0.f);
        }
    }
    {
        float* e = (float*)&w1;
        #pragma unroll
        for (int q = 0; q < 4; ++q) {
            const float x = e[q];
            const float r = sqrtf(fabsf(x) + 1e-8f) * inv;
            e[q] = (x > 0.f) ? r : ((x < 0.f) ? -r : 0.f);
        }
    }
    o[tid]        = w0;
    o[1024 + tid] = w1;
}

// ---------------------------------------------------------------------------
extern "C" void kernel_launch(void* const* d_in, const int* in_sizes, int n_in,
                              void* d_out, int out_size, void* d_ws, size_t ws_size,
                              hipStream_t stream)
{
    const float* x  = (const float*)d_in[0];   // [32, 512, 14, 14]
    const float* S1 = (const float*)d_in[1];   // [512, 8192]
    const float* S2 = (const float*)d_in[2];   // [512, 8192]
    float* out = (float*)d_out;                // [32, 8192]

    char* ws = (char*)d_ws;
    int*   p1    = (int*)(ws);                       // 2 KB
    int*   p2    = (int*)(ws + 2048);                // 2 KB
    float* xT    = (float*)(ws + 8192);              // 12.8 MB
    float* parts = (float*)(ws + 8192 + 12845056);   // 33.5 MB (1024 x 8192)

    prep<<<TR_BLOCKS + EX_BLOCKS, 256, 0, stream>>>(x, S1, S2, xT, p1, p2);
    gram_scatter<<<dim3(4, 4, NBATCH * 2), 256, 0, stream>>>(xT, p1, p2, parts);
    reduce_finalize<<<NBATCH, 1024, 0, stream>>>(parts, out);
}